// Round 8
// baseline (58.909 us; speedup 1.0000x reference)
//
#include <hip/hip_runtime.h>
#include <math.h>

#define BB 48
#define SS 1024
#define NCB (3 * BB)          // 144 combo-batches
#define NROW (BB * SS)
#define NBLK2 (NROW / 256)    // 192 epilogue blocks

typedef float f32x2 __attribute__((ext_vector_type(2)));

// ws layout: part[KS][NCB][SS] float4 | Qh | Kh | Vh (each [NCB][3][SS]) |
// partial[NBLK2][18]. Kernel stats overwrites part slice 0 with o in-place.
#define PROJ_ONE ((size_t)NCB * 3 * SS)

// Kernel P: per-band projections, planar layout. Q pre-scaled by
// (1/sqrt(3))*log2(e) so attn's v_exp_f32(q.k) == exp(q.k/sqrt(3)).
__global__ __launch_bounds__(256) void mbfca_proj(
    const float* __restrict__ x,
    const float* __restrict__ WQ, const float* __restrict__ bQ,
    const float* __restrict__ WK, const float* __restrict__ bK,
    const float* __restrict__ WV, const float* __restrict__ bV,
    float* __restrict__ Qh, float* __restrict__ Kh, float* __restrict__ Vh)
{
    const int bid   = blockIdx.x;        // 0..431
    const int which = bid % 3;           // 0=Q, 1=K, 2=V
    const int cb    = bid / 3;           // 0..143
    const int c     = cb / BB;
    const int b     = cb % BB;
    const int band  = (which == 0) ? (c + 2) % 3 : (which == 1) ? c : (c + 1) % 3;
    const float* W  = (which == 0) ? WQ : (which == 1) ? WK : WV;
    const float* Bi = (which == 0) ? bQ : (which == 1) ? bK : bV;
    const float scale = (which == 0)
        ? 0.57735026918962576f * 1.4426950408889634f : 1.0f;
    float* dst = ((which == 0) ? Qh : (which == 1) ? Kh : Vh)
                 + (size_t)cb * 3 * SS;
    const float* src = x + (size_t)(band * BB + b) * SS * 3;

    float w[9], bb[3];
    #pragma unroll
    for (int i = 0; i < 9; ++i) w[i] = W[band * 9 + i] * scale;
    #pragma unroll
    for (int i = 0; i < 3; ++i) bb[i] = Bi[band * 3 + i] * scale;

    const int tid = threadIdx.x;         // 4 positions per thread
    const float4* s4 = reinterpret_cast<const float4*>(src + 12 * tid);
    float4 A = s4[0], B4 = s4[1], C4 = s4[2];
    float a[12] = {A.x, A.y, A.z, A.w, B4.x, B4.y, B4.z, B4.w,
                   C4.x, C4.y, C4.z, C4.w};
    float o[3][4];
    #pragma unroll
    for (int j = 0; j < 4; ++j) {
        float a0 = a[3 * j], a1 = a[3 * j + 1], a2 = a[3 * j + 2];
        o[0][j] = w[0] * a0 + w[1] * a1 + w[2] * a2 + bb[0];
        o[1][j] = w[3] * a0 + w[4] * a1 + w[5] * a2 + bb[1];
        o[2][j] = w[6] * a0 + w[7] * a1 + w[8] * a2 + bb[2];
    }
    #pragma unroll
    for (int p = 0; p < 3; ++p)
        reinterpret_cast<float4*>(dst + (size_t)p * SS)[tid] =
            make_float4(o[p][0], o[p][1], o[p][2], o[p][3]);
}

// Kernel A: attention partials. No LDS, no barrier, no staging: K/V reads
// are wave-uniform (scalarizable / L1-resident), q reads coalesced float4.
template <int KSv>
__global__ __launch_bounds__(256) void mbfca_attn(
    const float* __restrict__ Qh, const float* __restrict__ Kh,
    const float* __restrict__ Vh, float* __restrict__ part)
{
    constexpr int SSK = SS / KSv;        // keys per slice
    const int bid   = blockIdx.x;
    const int slice = bid % KSv;
    const int cb    = bid / KSv;         // 0..143
    const int tid   = threadIdx.x;

    // 4 queries/thread from planar Q̂ (already scaled)
    const float* qbase = Qh + (size_t)cb * 3 * SS;
    float4 qv0 = reinterpret_cast<const float4*>(qbase + 0 * SS)[tid];
    float4 qv1 = reinterpret_cast<const float4*>(qbase + 1 * SS)[tid];
    float4 qv2 = reinterpret_cast<const float4*>(qbase + 2 * SS)[tid];
    f32x2 qp0[4] = {{qv0.x,qv0.x},{qv0.y,qv0.y},{qv0.z,qv0.z},{qv0.w,qv0.w}};
    f32x2 qp1[4] = {{qv1.x,qv1.x},{qv1.y,qv1.y},{qv1.z,qv1.z},{qv1.w,qv1.w}};
    f32x2 qp2[4] = {{qv2.x,qv2.x},{qv2.y,qv2.y},{qv2.z,qv2.z},{qv2.w,qv2.w}};

    const float* kbase = Kh + (size_t)cb * 3 * SS + slice * SSK;
    const float* vbase = Vh + (size_t)cb * 3 * SS + slice * SSK;
    const float4* K0 = reinterpret_cast<const float4*>(kbase + 0 * SS);
    const float4* K1 = reinterpret_cast<const float4*>(kbase + 1 * SS);
    const float4* K2 = reinterpret_cast<const float4*>(kbase + 2 * SS);
    const float4* V0 = reinterpret_cast<const float4*>(vbase + 0 * SS);
    const float4* V1 = reinterpret_cast<const float4*>(vbase + 1 * SS);
    const float4* V2 = reinterpret_cast<const float4*>(vbase + 2 * SS);

    f32x2 lac[4], a0[4], a1[4], a2[4];
    #pragma unroll
    for (int j = 0; j < 4; ++j) {
        lac[j] = (f32x2){0.f, 0.f};
        a0[j]  = (f32x2){0.f, 0.f};
        a1[j]  = (f32x2){0.f, 0.f};
        a2[j]  = (f32x2){0.f, 0.f};
    }

    #pragma unroll 2
    for (int t4 = 0; t4 < SSK / 4; ++t4) {
        float4 k0 = K0[t4], k1 = K1[t4], k2 = K2[t4];
        float4 v0 = V0[t4], v1 = V1[t4], v2 = V2[t4];
        f32x2 k0l = {k0.x, k0.y}, k0h = {k0.z, k0.w};
        f32x2 k1l = {k1.x, k1.y}, k1h = {k1.z, k1.w};
        f32x2 k2l = {k2.x, k2.y}, k2h = {k2.z, k2.w};
        f32x2 v0l = {v0.x, v0.y}, v0h = {v0.z, v0.w};
        f32x2 v1l = {v1.x, v1.y}, v1h = {v1.z, v1.w};
        f32x2 v2l = {v2.x, v2.y}, v2h = {v2.z, v2.w};
        #pragma unroll
        for (int j = 0; j < 4; ++j) {
            f32x2 sl = qp0[j] * k0l + qp1[j] * k1l + qp2[j] * k2l;
            f32x2 sh = qp0[j] * k0h + qp1[j] * k1h + qp2[j] * k2h;
            f32x2 pl, ph;
            pl.x = __builtin_amdgcn_exp2f(sl.x);
            pl.y = __builtin_amdgcn_exp2f(sl.y);
            ph.x = __builtin_amdgcn_exp2f(sh.x);
            ph.y = __builtin_amdgcn_exp2f(sh.y);
            lac[j] += pl + ph;
            a0[j]  += pl * v0l + ph * v0h;
            a1[j]  += pl * v1l + ph * v1h;
            a2[j]  += pl * v2l + ph * v2h;
        }
    }

    float4* dst = reinterpret_cast<float4*>(part) +
                  ((size_t)(slice * NCB + cb) * SS + 4 * tid);
    #pragma unroll
    for (int j = 0; j < 4; ++j)
        dst[j] = make_float4(a0[j].x + a0[j].y,
                             a1[j].x + a1[j].y,
                             a2[j].x + a2[j].y,
                             lac[j].x + lac[j].y);
}

// Kernel 2: reduce slices -> o (in-place to part slice 0), BN partials.
template <int KSv>
__global__ __launch_bounds__(256) void mbfca_stats(
    float* __restrict__ part, float* __restrict__ partial)
{
    const int r = blockIdx.x * 256 + threadIdx.x;   // row 0..49151
    const int b = r >> 10, s = r & 1023;
    __shared__ float red[4][18];

    float sums[18];
    #pragma unroll
    for (int k = 0; k < 18; ++k) sums[k] = 0.f;

    float4* p4 = reinterpret_cast<float4*>(part);
    #pragma unroll
    for (int c = 0; c < 3; ++c) {
        const int cb = c * BB + b;
        float4 t = make_float4(0.f, 0.f, 0.f, 0.f);
        #pragma unroll
        for (int sl = 0; sl < KSv; ++sl) {
            float4 u = p4[(size_t)(sl * NCB + cb) * SS + s];
            t.x += u.x; t.y += u.y; t.z += u.z; t.w += u.w;
        }
        float inv = 1.0f / t.w;
        float o0 = t.x * inv, o1 = t.y * inv, o2 = t.z * inv;
        p4[(size_t)cb * SS + s] = make_float4(o0, o1, o2, 0.f);  // in-place o
        sums[3 * c + 0] = o0;          sums[3 * c + 1] = o1;          sums[3 * c + 2] = o2;
        sums[9 + 3 * c + 0] = o0 * o0; sums[9 + 3 * c + 1] = o1 * o1; sums[9 + 3 * c + 2] = o2 * o2;
    }

    #pragma unroll
    for (int off = 32; off >= 1; off >>= 1)
        #pragma unroll
        for (int k = 0; k < 18; ++k)
            sums[k] += __shfl_xor(sums[k], off, 64);

    const int tid = threadIdx.x;
    if ((tid & 63) == 0) {
        #pragma unroll
        for (int k = 0; k < 18; ++k) red[tid >> 6][k] = sums[k];
    }
    __syncthreads();
    if (tid < 18)
        partial[blockIdx.x * 18 + tid] =
            red[0][tid] + red[1][tid] + red[2][tid] + red[3][tid];
}

// Kernel 3: reduce per-block partials -> BN scale/shift; compact o -> y.
__global__ __launch_bounds__(256) void mbfca_bnfc(
    const float* __restrict__ part, const float* __restrict__ partial,
    const float* __restrict__ gamma, const float* __restrict__ beta,
    const float* __restrict__ fcw, const float* __restrict__ fcb,
    float* __restrict__ out)
{
    __shared__ float red[4][18];
    __shared__ float accs[18];
    const int tid = threadIdx.x;

    float sums[18];
    #pragma unroll
    for (int k = 0; k < 18; ++k) sums[k] = 0.f;
    if (tid < NBLK2) {
        #pragma unroll
        for (int k = 0; k < 18; ++k) sums[k] = partial[tid * 18 + k];
    }
    #pragma unroll
    for (int off = 32; off >= 1; off >>= 1)
        #pragma unroll
        for (int k = 0; k < 18; ++k)
            sums[k] += __shfl_xor(sums[k], off, 64);
    if ((tid & 63) == 0) {
        #pragma unroll
        for (int k = 0; k < 18; ++k) red[tid >> 6][k] = sums[k];
    }
    __syncthreads();
    if (tid < 18)
        accs[tid] = red[0][tid] + red[1][tid] + red[2][tid] + red[3][tid];
    __syncthreads();

    const int r = blockIdx.x * 256 + tid;
    const int b = r >> 10, s = r & 1023;
    const float invN = 1.0f / (float)NROW;

    float sc[9], sh[9];
    #pragma unroll
    for (int ch = 0; ch < 9; ++ch) {
        float mean = accs[ch] * invN;
        float var  = accs[9 + ch] * invN - mean * mean;  // biased variance
        float sfac = gamma[ch] * rsqrtf(var + 1e-5f);
        sc[ch] = sfac;
        sh[ch] = beta[ch] - mean * sfac;
    }

    const float4* p4 = reinterpret_cast<const float4*>(part);
    float y0 = fcb[0], y1 = fcb[1], y2 = fcb[2];
    #pragma unroll
    for (int c = 0; c < 3; ++c) {
        const int cb = c * BB + b;
        float4 t = p4[(size_t)cb * SS + s];
        float o[3] = {t.x, t.y, t.z};
        #pragma unroll
        for (int e = 0; e < 3; ++e) {
            float n = o[e] * sc[3 * c + e] + sh[3 * c + e];
            y0 += n * fcw[3 * c + e];
            y1 += n * fcw[9 + 3 * c + e];
            y2 += n * fcw[18 + 3 * c + e];
        }
    }
    out[r * 3 + 0] = y0;
    out[r * 3 + 1] = y1;
    out[r * 3 + 2] = y2;
}

template <int KSv>
static void run_pipeline(const float* x, const float* WQ, const float* bQ,
                         const float* WK, const float* bK,
                         const float* WV, const float* bV,
                         const float* gamma, const float* beta,
                         const float* fcw, const float* fcb,
                         float* ws, float* out, hipStream_t stream)
{
    float* part = ws;
    float* Qh   = part + (size_t)KSv * NCB * SS * 4;
    float* Kh   = Qh + PROJ_ONE;
    float* Vh   = Kh + PROJ_ONE;
    float* partial = Vh + PROJ_ONE;

    mbfca_proj<<<dim3(NCB * 3), dim3(256), 0, stream>>>(
        x, WQ, bQ, WK, bK, WV, bV, Qh, Kh, Vh);
    mbfca_attn<KSv><<<dim3(NCB * KSv), dim3(256), 0, stream>>>(
        Qh, Kh, Vh, part);
    mbfca_stats<KSv><<<dim3(NBLK2), dim3(256), 0, stream>>>(part, partial);
    mbfca_bnfc<<<dim3(NBLK2), dim3(256), 0, stream>>>(
        part, partial, gamma, beta, fcw, fcb, out);
}

extern "C" void kernel_launch(void* const* d_in, const int* in_sizes, int n_in,
                              void* d_out, int out_size, void* d_ws, size_t ws_size,
                              hipStream_t stream)
{
    const float* x     = (const float*)d_in[0];
    const float* WQ    = (const float*)d_in[1];
    const float* bQv   = (const float*)d_in[2];
    const float* WK    = (const float*)d_in[3];
    const float* bKv   = (const float*)d_in[4];
    const float* WV    = (const float*)d_in[5];
    const float* bVv   = (const float*)d_in[6];
    const float* gamma = (const float*)d_in[7];
    const float* beta  = (const float*)d_in[8];
    const float* fcw   = (const float*)d_in[9];
    const float* fcb   = (const float*)d_in[10];

    float* ws = (float*)d_ws;

    const size_t tail = 3 * PROJ_ONE * sizeof(float)
                      + (size_t)NBLK2 * 18 * sizeof(float);
    const size_t need8 = (size_t)8 * NCB * SS * 4 * sizeof(float) + tail;

    if (ws_size >= need8) {
        run_pipeline<8>(x, WQ, bQv, WK, bKv, WV, bVv, gamma, beta, fcw, fcb,
                        ws, (float*)d_out, stream);
    } else {
        run_pipeline<4>(x, WQ, bQv, WK, bKv, WV, bVv, gamma, beta, fcw, fcb,
                        ws, (float*)d_out, stream);
    }
}

// Round 9
// 57.074 us; speedup vs baseline: 1.0322x; 1.0322x over previous
//
#include <hip/hip_runtime.h>
#include <math.h>

#define BB 48
#define SS 1024
#define NCB (3 * BB)          // 144 combo-batches
#define NROW (BB * SS)
#define NBLK2 (NROW / 256)    // 192 epilogue blocks

typedef float f32x2 __attribute__((ext_vector_type(2)));

// ws layout: part[KS][NCB][SS] float4 (A0,A1,A2,l) | partial[NBLK2][18].
// stats overwrites part slice 0 with o in-place (race-free, 1 thread/slot).

// Kernel A: projection (K/V once per block into LDS, Q per-thread) +
// no-max single-pass attention partials. 128 threads, 8 queries/thread
// (covers all 1024 queries), SSK keys per block. 6 broadcast ds_read_b128
// per 2048 pairs -> LDS pipe ~8.6 us; packed f32x2 VALU ~15 us; exp ~8 us.
template <int KSv>
__global__ __launch_bounds__(128) void mbfca_attn(
    const float* __restrict__ x,
    const float* __restrict__ WQ, const float* __restrict__ bQ,
    const float* __restrict__ WK, const float* __restrict__ bK,
    const float* __restrict__ WV, const float* __restrict__ bV,
    float* __restrict__ part)
{
    constexpr int SSK = SS / KSv;        // keys per slice (64 at KS=16)
    const int bid   = blockIdx.x;
    const int slice = bid % KSv;
    const int cb    = bid / KSv;         // 0..143
    const int c     = cb / BB;
    const int b     = cb % BB;
    const int kband = c;
    const int vband = (c + 1) % 3;
    const int qband = (c + 2) % 3;

    __shared__ __align__(16) float Ksm[3][SSK];
    __shared__ __align__(16) float Vsm[3][SSK];

    const int tid = threadIdx.x;

    const float* xk = x + (size_t)(kband * BB + b) * SS * 3;
    const float* xv = x + (size_t)(vband * BB + b) * SS * 3;
    const float* xq = x + (size_t)(qband * BB + b) * SS * 3;

    // stage this slice's projected K,V (SSK keys; one-time)
    {
        float wk[9], wv[9], bk[3], bv[3];
        #pragma unroll
        for (int i = 0; i < 9; ++i) { wk[i] = WK[kband * 9 + i]; wv[i] = WV[vband * 9 + i]; }
        #pragma unroll
        for (int i = 0; i < 3; ++i) { bk[i] = bK[kband * 3 + i]; bv[i] = bV[vband * 3 + i]; }
        for (int t = tid; t < SSK; t += 128) {
            const int tk = slice * SSK + t;
            float a0 = xk[tk * 3 + 0], a1 = xk[tk * 3 + 1], a2 = xk[tk * 3 + 2];
            Ksm[0][t] = wk[0] * a0 + wk[1] * a1 + wk[2] * a2 + bk[0];
            Ksm[1][t] = wk[3] * a0 + wk[4] * a1 + wk[5] * a2 + bk[1];
            Ksm[2][t] = wk[6] * a0 + wk[7] * a1 + wk[8] * a2 + bk[2];
            float c0 = xv[tk * 3 + 0], c1 = xv[tk * 3 + 1], c2 = xv[tk * 3 + 2];
            Vsm[0][t] = wv[0] * c0 + wv[1] * c1 + wv[2] * c2 + bv[0];
            Vsm[1][t] = wv[3] * c0 + wv[4] * c1 + wv[5] * c2 + bv[1];
            Vsm[2][t] = wv[6] * c0 + wv[7] * c1 + wv[8] * c2 + bv[2];
        }
    }
    __syncthreads();

    // 8 queries/thread: s = 8*tid + j. qscale = (1/sqrt(3))*log2(e) so
    // v_exp_f32(q'.k) == exp(q.k/sqrt(3)). q duplicated into f32x2 lanes.
    f32x2 qp0[8], qp1[8], qp2[8];
    {
        float wq[9], bq[3];
        const float qscale = 0.57735026918962576f * 1.4426950408889634f;
        #pragma unroll
        for (int i = 0; i < 9; ++i) wq[i] = WQ[qband * 9 + i] * qscale;
        #pragma unroll
        for (int i = 0; i < 3; ++i) bq[i] = bQ[qband * 3 + i] * qscale;
        const float4* xq4 = reinterpret_cast<const float4*>(xq + 24 * tid);
        float a[24];
        #pragma unroll
        for (int v = 0; v < 6; ++v) {
            float4 f = xq4[v];
            a[4 * v + 0] = f.x; a[4 * v + 1] = f.y;
            a[4 * v + 2] = f.z; a[4 * v + 3] = f.w;
        }
        #pragma unroll
        for (int j = 0; j < 8; ++j) {
            float a0 = a[3 * j], a1 = a[3 * j + 1], a2 = a[3 * j + 2];
            float t0 = wq[0] * a0 + wq[1] * a1 + wq[2] * a2 + bq[0];
            float t1 = wq[3] * a0 + wq[4] * a1 + wq[5] * a2 + bq[1];
            float t2 = wq[6] * a0 + wq[7] * a1 + wq[8] * a2 + bq[2];
            qp0[j] = (f32x2){t0, t0};
            qp1[j] = (f32x2){t1, t1};
            qp2[j] = (f32x2){t2, t2};
        }
    }

    f32x2 lac[8], a0[8], a1[8], a2[8];
    #pragma unroll
    for (int j = 0; j < 8; ++j) {
        lac[j] = (f32x2){0.f, 0.f};
        a0[j]  = (f32x2){0.f, 0.f};
        a1[j]  = (f32x2){0.f, 0.f};
        a2[j]  = (f32x2){0.f, 0.f};
    }

    const float4* K0 = reinterpret_cast<const float4*>(&Ksm[0][0]);
    const float4* K1 = reinterpret_cast<const float4*>(&Ksm[1][0]);
    const float4* K2 = reinterpret_cast<const float4*>(&Ksm[2][0]);
    const float4* V0 = reinterpret_cast<const float4*>(&Vsm[0][0]);
    const float4* V1 = reinterpret_cast<const float4*>(&Vsm[1][0]);
    const float4* V2 = reinterpret_cast<const float4*>(&Vsm[2][0]);

    for (int t4 = 0; t4 < SSK / 4; ++t4) {
        float4 k0 = K0[t4], k1 = K1[t4], k2 = K2[t4];
        float4 v0 = V0[t4], v1 = V1[t4], v2 = V2[t4];
        f32x2 k0l = {k0.x, k0.y}, k0h = {k0.z, k0.w};
        f32x2 k1l = {k1.x, k1.y}, k1h = {k1.z, k1.w};
        f32x2 k2l = {k2.x, k2.y}, k2h = {k2.z, k2.w};
        f32x2 v0l = {v0.x, v0.y}, v0h = {v0.z, v0.w};
        f32x2 v1l = {v1.x, v1.y}, v1h = {v1.z, v1.w};
        f32x2 v2l = {v2.x, v2.y}, v2h = {v2.z, v2.w};
        #pragma unroll
        for (int j = 0; j < 8; ++j) {
            f32x2 sl = qp0[j] * k0l + qp1[j] * k1l + qp2[j] * k2l;
            f32x2 sh = qp0[j] * k0h + qp1[j] * k1h + qp2[j] * k2h;
            f32x2 pl, ph;
            pl.x = __builtin_amdgcn_exp2f(sl.x);
            pl.y = __builtin_amdgcn_exp2f(sl.y);
            ph.x = __builtin_amdgcn_exp2f(sh.x);
            ph.y = __builtin_amdgcn_exp2f(sh.y);
            lac[j] += pl + ph;
            a0[j]  += pl * v0l + ph * v0h;
            a1[j]  += pl * v1l + ph * v1h;
            a2[j]  += pl * v2l + ph * v2h;
        }
    }

    // store part[slice][cb][8*tid+j] (contiguous float4 runs, coalesced)
    float4* dst = reinterpret_cast<float4*>(part) +
                  ((size_t)(slice * NCB + cb) * SS + 8 * tid);
    #pragma unroll
    for (int j = 0; j < 8; ++j)
        dst[j] = make_float4(a0[j].x + a0[j].y,
                             a1[j].x + a1[j].y,
                             a2[j].x + a2[j].y,
                             lac[j].x + lac[j].y);
}

// Kernel 2: reduce slices -> o (in-place to part slice 0), BN partials.
template <int KSv>
__global__ __launch_bounds__(256) void mbfca_stats(
    float* __restrict__ part, float* __restrict__ partial)
{
    const int r = blockIdx.x * 256 + threadIdx.x;   // row 0..49151
    const int b = r >> 10, s = r & 1023;
    __shared__ float red[4][18];

    float sums[18];
    #pragma unroll
    for (int k = 0; k < 18; ++k) sums[k] = 0.f;

    float4* p4 = reinterpret_cast<float4*>(part);
    #pragma unroll
    for (int c = 0; c < 3; ++c) {
        const int cb = c * BB + b;
        float4 t = make_float4(0.f, 0.f, 0.f, 0.f);
        #pragma unroll
        for (int sl = 0; sl < KSv; ++sl) {
            float4 u = p4[(size_t)(sl * NCB + cb) * SS + s];
            t.x += u.x; t.y += u.y; t.z += u.z; t.w += u.w;
        }
        float inv = 1.0f / t.w;
        float o0 = t.x * inv, o1 = t.y * inv, o2 = t.z * inv;
        p4[(size_t)cb * SS + s] = make_float4(o0, o1, o2, 0.f);  // in-place o
        sums[3 * c + 0] = o0;          sums[3 * c + 1] = o1;          sums[3 * c + 2] = o2;
        sums[9 + 3 * c + 0] = o0 * o0; sums[9 + 3 * c + 1] = o1 * o1; sums[9 + 3 * c + 2] = o2 * o2;
    }

    #pragma unroll
    for (int off = 32; off >= 1; off >>= 1)
        #pragma unroll
        for (int k = 0; k < 18; ++k)
            sums[k] += __shfl_xor(sums[k], off, 64);

    const int tid = threadIdx.x;
    if ((tid & 63) == 0) {
        #pragma unroll
        for (int k = 0; k < 18; ++k) red[tid >> 6][k] = sums[k];
    }
    __syncthreads();
    if (tid < 18)
        partial[blockIdx.x * 18 + tid] =
            red[0][tid] + red[1][tid] + red[2][tid] + red[3][tid];
}

// Kernel 3: reduce per-block partials -> BN scale/shift; compact o -> y.
__global__ __launch_bounds__(256) void mbfca_bnfc(
    const float* __restrict__ part, const float* __restrict__ partial,
    const float* __restrict__ gamma, const float* __restrict__ beta,
    const float* __restrict__ fcw, const float* __restrict__ fcb,
    float* __restrict__ out)
{
    __shared__ float red[4][18];
    __shared__ float accs[18];
    const int tid = threadIdx.x;

    float sums[18];
    #pragma unroll
    for (int k = 0; k < 18; ++k) sums[k] = 0.f;
    if (tid < NBLK2) {
        #pragma unroll
        for (int k = 0; k < 18; ++k) sums[k] = partial[tid * 18 + k];
    }
    #pragma unroll
    for (int off = 32; off >= 1; off >>= 1)
        #pragma unroll
        for (int k = 0; k < 18; ++k)
            sums[k] += __shfl_xor(sums[k], off, 64);
    if ((tid & 63) == 0) {
        #pragma unroll
        for (int k = 0; k < 18; ++k) red[tid >> 6][k] = sums[k];
    }
    __syncthreads();
    if (tid < 18)
        accs[tid] = red[0][tid] + red[1][tid] + red[2][tid] + red[3][tid];
    __syncthreads();

    const int r = blockIdx.x * 256 + tid;
    const int b = r >> 10, s = r & 1023;
    const float invN = 1.0f / (float)NROW;

    float sc[9], sh[9];
    #pragma unroll
    for (int ch = 0; ch < 9; ++ch) {
        float mean = accs[ch] * invN;
        float var  = accs[9 + ch] * invN - mean * mean;  // biased variance
        float sfac = gamma[ch] * rsqrtf(var + 1e-5f);
        sc[ch] = sfac;
        sh[ch] = beta[ch] - mean * sfac;
    }

    const float4* p4 = reinterpret_cast<const float4*>(part);
    float y0 = fcb[0], y1 = fcb[1], y2 = fcb[2];
    #pragma unroll
    for (int c = 0; c < 3; ++c) {
        const int cb = c * BB + b;
        float4 t = p4[(size_t)cb * SS + s];
        float o[3] = {t.x, t.y, t.z};
        #pragma unroll
        for (int e = 0; e < 3; ++e) {
            float n = o[e] * sc[3 * c + e] + sh[3 * c + e];
            y0 += n * fcw[3 * c + e];
            y1 += n * fcw[9 + 3 * c + e];
            y2 += n * fcw[18 + 3 * c + e];
        }
    }
    out[r * 3 + 0] = y0;
    out[r * 3 + 1] = y1;
    out[r * 3 + 2] = y2;
}

template <int KSv>
static void run_pipeline(const float* x, const float* WQ, const float* bQ,
                         const float* WK, const float* bK,
                         const float* WV, const float* bV,
                         const float* gamma, const float* beta,
                         const float* fcw, const float* fcb,
                         float* ws, float* out, hipStream_t stream)
{
    float* part    = ws;
    float* partial = part + (size_t)KSv * NCB * SS * 4;

    mbfca_attn<KSv><<<dim3(NCB * KSv), dim3(128), 0, stream>>>(
        x, WQ, bQ, WK, bK, WV, bV, part);
    mbfca_stats<KSv><<<dim3(NBLK2), dim3(256), 0, stream>>>(part, partial);
    mbfca_bnfc<<<dim3(NBLK2), dim3(256), 0, stream>>>(
        part, partial, gamma, beta, fcw, fcb, out);
}

extern "C" void kernel_launch(void* const* d_in, const int* in_sizes, int n_in,
                              void* d_out, int out_size, void* d_ws, size_t ws_size,
                              hipStream_t stream)
{
    const float* x     = (const float*)d_in[0];
    const float* WQ    = (const float*)d_in[1];
    const float* bQv   = (const float*)d_in[2];
    const float* WK    = (const float*)d_in[3];
    const float* bKv   = (const float*)d_in[4];
    const float* WV    = (const float*)d_in[5];
    const float* bVv   = (const float*)d_in[6];
    const float* gamma = (const float*)d_in[7];
    const float* beta  = (const float*)d_in[8];
    const float* fcw   = (const float*)d_in[9];
    const float* fcb   = (const float*)d_in[10];

    float* ws = (float*)d_ws;

    const size_t tail   = (size_t)NBLK2 * 18 * sizeof(float);
    const size_t need16 = (size_t)16 * NCB * SS * 4 * sizeof(float) + tail;
    const size_t need8  = (size_t)8  * NCB * SS * 4 * sizeof(float) + tail;

    if (ws_size >= need16) {
        run_pipeline<16>(x, WQ, bQv, WK, bKv, WV, bVv, gamma, beta, fcw, fcb,
                         ws, (float*)d_out, stream);
    } else if (ws_size >= need8) {
        run_pipeline<8>(x, WQ, bQv, WK, bKv, WV, bVv, gamma, beta, fcw, fcb,
                        ws, (float*)d_out, stream);
    } else {
        run_pipeline<4>(x, WQ, bQv, WK, bKv, WV, bVv, gamma, beta, fcw, fcb,
                        ws, (float*)d_out, stream);
    }
}

// Round 10
// 52.621 us; speedup vs baseline: 1.1195x; 1.0846x over previous
//
#include <hip/hip_runtime.h>
#include <math.h>

#define BB 48
#define SS 1024
#define NCB (3 * BB)          // 144 combo-batches
#define NROW (BB * SS)
#define NBLK2 (NROW / 256)    // 192 epilogue blocks

typedef float f32x2 __attribute__((ext_vector_type(2)));

// ws layout: part[KS][NCB][SS] float4 (A0,A1,A2,l) | partial[NBLK2][18].
// stats overwrites part slice 0 with o in-place (race-free, 1 thread/slot).

// Kernel A: projection + no-max single-pass attention partials.
// KS=16, 256 threads, 4 queries/thread. Register-double-buffered K/V
// (prefetch next iter), batched score->exp->accum for exp-latency distance.
template <int KSv>
__global__ __launch_bounds__(256) void mbfca_attn(
    const float* __restrict__ x,
    const float* __restrict__ WQ, const float* __restrict__ bQ,
    const float* __restrict__ WK, const float* __restrict__ bK,
    const float* __restrict__ WV, const float* __restrict__ bV,
    float* __restrict__ part)
{
    constexpr int SSK = SS / KSv;        // keys per slice
    constexpr int NIT = SSK / 4;         // inner iterations
    const int bid   = blockIdx.x;
    const int slice = bid % KSv;
    const int cb    = bid / KSv;         // 0..143
    const int c     = cb / BB;
    const int b     = cb % BB;
    const int kband = c;
    const int vband = (c + 1) % 3;
    const int qband = (c + 2) % 3;

    __shared__ __align__(16) float Ksm[3][SSK];
    __shared__ __align__(16) float Vsm[3][SSK];

    const int tid = threadIdx.x;

    const float* xk = x + (size_t)(kband * BB + b) * SS * 3;
    const float* xv = x + (size_t)(vband * BB + b) * SS * 3;
    const float* xq = x + (size_t)(qband * BB + b) * SS * 3;

    // stage this slice's projected K,V
    {
        float wk[9], wv[9], bk[3], bv[3];
        #pragma unroll
        for (int i = 0; i < 9; ++i) { wk[i] = WK[kband * 9 + i]; wv[i] = WV[vband * 9 + i]; }
        #pragma unroll
        for (int i = 0; i < 3; ++i) { bk[i] = bK[kband * 3 + i]; bv[i] = bV[vband * 3 + i]; }
        for (int t = tid; t < SSK; t += 256) {
            const int tk = slice * SSK + t;
            float a0 = xk[tk * 3 + 0], a1 = xk[tk * 3 + 1], a2 = xk[tk * 3 + 2];
            Ksm[0][t] = wk[0] * a0 + wk[1] * a1 + wk[2] * a2 + bk[0];
            Ksm[1][t] = wk[3] * a0 + wk[4] * a1 + wk[5] * a2 + bk[1];
            Ksm[2][t] = wk[6] * a0 + wk[7] * a1 + wk[8] * a2 + bk[2];
            float c0 = xv[tk * 3 + 0], c1 = xv[tk * 3 + 1], c2 = xv[tk * 3 + 2];
            Vsm[0][t] = wv[0] * c0 + wv[1] * c1 + wv[2] * c2 + bv[0];
            Vsm[1][t] = wv[3] * c0 + wv[4] * c1 + wv[5] * c2 + bv[1];
            Vsm[2][t] = wv[6] * c0 + wv[7] * c1 + wv[8] * c2 + bv[2];
        }
    }
    __syncthreads();

    // 4 queries/thread: s = 4*tid + j, pre-scaled by (1/sqrt(3))*log2(e)
    f32x2 qp0[4], qp1[4], qp2[4];
    {
        float wq[9], bq[3];
        const float qscale = 0.57735026918962576f * 1.4426950408889634f;
        #pragma unroll
        for (int i = 0; i < 9; ++i) wq[i] = WQ[qband * 9 + i] * qscale;
        #pragma unroll
        for (int i = 0; i < 3; ++i) bq[i] = bQ[qband * 3 + i] * qscale;
        const float4* xq4 = reinterpret_cast<const float4*>(xq + 12 * tid);
        float4 A = xq4[0], B4 = xq4[1], C4 = xq4[2];
        float a[12] = {A.x, A.y, A.z, A.w, B4.x, B4.y, B4.z, B4.w,
                       C4.x, C4.y, C4.z, C4.w};
        #pragma unroll
        for (int j = 0; j < 4; ++j) {
            float a0 = a[3 * j], a1 = a[3 * j + 1], a2 = a[3 * j + 2];
            float t0 = wq[0] * a0 + wq[1] * a1 + wq[2] * a2 + bq[0];
            float t1 = wq[3] * a0 + wq[4] * a1 + wq[5] * a2 + bq[1];
            float t2 = wq[6] * a0 + wq[7] * a1 + wq[8] * a2 + bq[2];
            qp0[j] = (f32x2){t0, t0};
            qp1[j] = (f32x2){t1, t1};
            qp2[j] = (f32x2){t2, t2};
        }
    }

    f32x2 lac[4], a0[4], a1[4], a2[4];
    #pragma unroll
    for (int j = 0; j < 4; ++j) {
        lac[j] = (f32x2){0.f, 0.f};
        a0[j]  = (f32x2){0.f, 0.f};
        a1[j]  = (f32x2){0.f, 0.f};
        a2[j]  = (f32x2){0.f, 0.f};
    }

    const float4* K0 = reinterpret_cast<const float4*>(&Ksm[0][0]);
    const float4* K1 = reinterpret_cast<const float4*>(&Ksm[1][0]);
    const float4* K2 = reinterpret_cast<const float4*>(&Ksm[2][0]);
    const float4* V0 = reinterpret_cast<const float4*>(&Vsm[0][0]);
    const float4* V1 = reinterpret_cast<const float4*>(&Vsm[1][0]);
    const float4* V2 = reinterpret_cast<const float4*>(&Vsm[2][0]);

    // batched body: scores -> exps -> accumulates (exp-latency distance)
    auto body = [&](float4 k0, float4 k1, float4 k2,
                    float4 v0, float4 v1, float4 v2) {
        f32x2 k0l = {k0.x, k0.y}, k0h = {k0.z, k0.w};
        f32x2 k1l = {k1.x, k1.y}, k1h = {k1.z, k1.w};
        f32x2 k2l = {k2.x, k2.y}, k2h = {k2.z, k2.w};
        f32x2 v0l = {v0.x, v0.y}, v0h = {v0.z, v0.w};
        f32x2 v1l = {v1.x, v1.y}, v1h = {v1.z, v1.w};
        f32x2 v2l = {v2.x, v2.y}, v2h = {v2.z, v2.w};
        f32x2 sl[4], sh[4];
        #pragma unroll
        for (int j = 0; j < 4; ++j) {
            sl[j] = qp0[j] * k0l + qp1[j] * k1l + qp2[j] * k2l;
            sh[j] = qp0[j] * k0h + qp1[j] * k1h + qp2[j] * k2h;
        }
        f32x2 pl[4], ph[4];
        #pragma unroll
        for (int j = 0; j < 4; ++j) {
            pl[j].x = __builtin_amdgcn_exp2f(sl[j].x);
            pl[j].y = __builtin_amdgcn_exp2f(sl[j].y);
            ph[j].x = __builtin_amdgcn_exp2f(sh[j].x);
            ph[j].y = __builtin_amdgcn_exp2f(sh[j].y);
        }
        #pragma unroll
        for (int j = 0; j < 4; ++j) {
            lac[j] += pl[j] + ph[j];
            a0[j]  += pl[j] * v0l + ph[j] * v0h;
            a1[j]  += pl[j] * v1l + ph[j] * v1h;
            a2[j]  += pl[j] * v2l + ph[j] * v2h;
        }
    };

    // register double-buffer: prefetch t4+1 while computing t4
    float4 k0 = K0[0], k1 = K1[0], k2 = K2[0];
    float4 v0 = V0[0], v1 = V1[0], v2 = V2[0];
    #pragma unroll 2
    for (int t4 = 0; t4 < NIT - 1; ++t4) {
        float4 nk0 = K0[t4 + 1], nk1 = K1[t4 + 1], nk2 = K2[t4 + 1];
        float4 nv0 = V0[t4 + 1], nv1 = V1[t4 + 1], nv2 = V2[t4 + 1];
        body(k0, k1, k2, v0, v1, v2);
        k0 = nk0; k1 = nk1; k2 = nk2;
        v0 = nv0; v1 = nv1; v2 = nv2;
    }
    body(k0, k1, k2, v0, v1, v2);

    float4* dst = reinterpret_cast<float4*>(part) +
                  ((size_t)(slice * NCB + cb) * SS + 4 * tid);
    #pragma unroll
    for (int j = 0; j < 4; ++j)
        dst[j] = make_float4(a0[j].x + a0[j].y,
                             a1[j].x + a1[j].y,
                             a2[j].x + a2[j].y,
                             lac[j].x + lac[j].y);
}

// Kernel 2: reduce slices -> o (in-place to part slice 0), BN partials.
template <int KSv>
__global__ __launch_bounds__(256) void mbfca_stats(
    float* __restrict__ part, float* __restrict__ partial)
{
    const int r = blockIdx.x * 256 + threadIdx.x;   // row 0..49151
    const int b = r >> 10, s = r & 1023;
    __shared__ float red[4][18];

    float sums[18];
    #pragma unroll
    for (int k = 0; k < 18; ++k) sums[k] = 0.f;

    float4* p4 = reinterpret_cast<float4*>(part);
    #pragma unroll
    for (int c = 0; c < 3; ++c) {
        const int cb = c * BB + b;
        float4 t = make_float4(0.f, 0.f, 0.f, 0.f);
        #pragma unroll
        for (int sl = 0; sl < KSv; ++sl) {
            float4 u = p4[(size_t)(sl * NCB + cb) * SS + s];
            t.x += u.x; t.y += u.y; t.z += u.z; t.w += u.w;
        }
        float inv = 1.0f / t.w;
        float o0 = t.x * inv, o1 = t.y * inv, o2 = t.z * inv;
        p4[(size_t)cb * SS + s] = make_float4(o0, o1, o2, 0.f);  // in-place o
        sums[3 * c + 0] = o0;          sums[3 * c + 1] = o1;          sums[3 * c + 2] = o2;
        sums[9 + 3 * c + 0] = o0 * o0; sums[9 + 3 * c + 1] = o1 * o1; sums[9 + 3 * c + 2] = o2 * o2;
    }

    #pragma unroll
    for (int off = 32; off >= 1; off >>= 1)
        #pragma unroll
        for (int k = 0; k < 18; ++k)
            sums[k] += __shfl_xor(sums[k], off, 64);

    const int tid = threadIdx.x;
    if ((tid & 63) == 0) {
        #pragma unroll
        for (int k = 0; k < 18; ++k) red[tid >> 6][k] = sums[k];
    }
    __syncthreads();
    if (tid < 18)
        partial[blockIdx.x * 18 + tid] =
            red[0][tid] + red[1][tid] + red[2][tid] + red[3][tid];
}

// Kernel 3: reduce per-block partials -> BN scale/shift; compact o -> y.
__global__ __launch_bounds__(256) void mbfca_bnfc(
    const float* __restrict__ part, const float* __restrict__ partial,
    const float* __restrict__ gamma, const float* __restrict__ beta,
    const float* __restrict__ fcw, const float* __restrict__ fcb,
    float* __restrict__ out)
{
    __shared__ float red[4][18];
    __shared__ float accs[18];
    const int tid = threadIdx.x;

    float sums[18];
    #pragma unroll
    for (int k = 0; k < 18; ++k) sums[k] = 0.f;
    if (tid < NBLK2) {
        #pragma unroll
        for (int k = 0; k < 18; ++k) sums[k] = partial[tid * 18 + k];
    }
    #pragma unroll
    for (int off = 32; off >= 1; off >>= 1)
        #pragma unroll
        for (int k = 0; k < 18; ++k)
            sums[k] += __shfl_xor(sums[k], off, 64);
    if ((tid & 63) == 0) {
        #pragma unroll
        for (int k = 0; k < 18; ++k) red[tid >> 6][k] = sums[k];
    }
    __syncthreads();
    if (tid < 18)
        accs[tid] = red[0][tid] + red[1][tid] + red[2][tid] + red[3][tid];
    __syncthreads();

    const int r = blockIdx.x * 256 + tid;
    const int b = r >> 10, s = r & 1023;
    const float invN = 1.0f / (float)NROW;

    float sc[9], sh[9];
    #pragma unroll
    for (int ch = 0; ch < 9; ++ch) {
        float mean = accs[ch] * invN;
        float var  = accs[9 + ch] * invN - mean * mean;  // biased variance
        float sfac = gamma[ch] * rsqrtf(var + 1e-5f);
        sc[ch] = sfac;
        sh[ch] = beta[ch] - mean * sfac;
    }

    const float4* p4 = reinterpret_cast<const float4*>(part);
    float y0 = fcb[0], y1 = fcb[1], y2 = fcb[2];
    #pragma unroll
    for (int c = 0; c < 3; ++c) {
        const int cb = c * BB + b;
        float4 t = p4[(size_t)cb * SS + s];
        float o[3] = {t.x, t.y, t.z};
        #pragma unroll
        for (int e = 0; e < 3; ++e) {
            float n = o[e] * sc[3 * c + e] + sh[3 * c + e];
            y0 += n * fcw[3 * c + e];
            y1 += n * fcw[9 + 3 * c + e];
            y2 += n * fcw[18 + 3 * c + e];
        }
    }
    out[r * 3 + 0] = y0;
    out[r * 3 + 1] = y1;
    out[r * 3 + 2] = y2;
}

template <int KSv>
static void run_pipeline(const float* x, const float* WQ, const float* bQ,
                         const float* WK, const float* bK,
                         const float* WV, const float* bV,
                         const float* gamma, const float* beta,
                         const float* fcw, const float* fcb,
                         float* ws, float* out, hipStream_t stream)
{
    float* part    = ws;
    float* partial = part + (size_t)KSv * NCB * SS * 4;

    mbfca_attn<KSv><<<dim3(NCB * KSv), dim3(256), 0, stream>>>(
        x, WQ, bQ, WK, bK, WV, bV, part);
    mbfca_stats<KSv><<<dim3(NBLK2), dim3(256), 0, stream>>>(part, partial);
    mbfca_bnfc<<<dim3(NBLK2), dim3(256), 0, stream>>>(
        part, partial, gamma, beta, fcw, fcb, out);
}

extern "C" void kernel_launch(void* const* d_in, const int* in_sizes, int n_in,
                              void* d_out, int out_size, void* d_ws, size_t ws_size,
                              hipStream_t stream)
{
    const float* x     = (const float*)d_in[0];
    const float* WQ    = (const float*)d_in[1];
    const float* bQv   = (const float*)d_in[2];
    const float* WK    = (const float*)d_in[3];
    const float* bKv   = (const float*)d_in[4];
    const float* WV    = (const float*)d_in[5];
    const float* bVv   = (const float*)d_in[6];
    const float* gamma = (const float*)d_in[7];
    const float* beta  = (const float*)d_in[8];
    const float* fcw   = (const float*)d_in[9];
    const float* fcb   = (const float*)d_in[10];

    float* ws = (float*)d_ws;

    const size_t tail   = (size_t)NBLK2 * 18 * sizeof(float);
    const size_t need16 = (size_t)16 * NCB * SS * 4 * sizeof(float) + tail;
    const size_t need8  = (size_t)8  * NCB * SS * 4 * sizeof(float) + tail;

    if (ws_size >= need16) {
        run_pipeline<16>(x, WQ, bQv, WK, bKv, WV, bVv, gamma, beta, fcw, fcb,
                         ws, (float*)d_out, stream);
    } else if (ws_size >= need8) {
        run_pipeline<8>(x, WQ, bQv, WK, bKv, WV, bVv, gamma, beta, fcw, fcb,
                        ws, (float*)d_out, stream);
    } else {
        run_pipeline<4>(x, WQ, bQv, WK, bKv, WV, bVv, gamma, beta, fcw, fcb,
                        ws, (float*)d_out, stream);
    }
}